// Round 5
// baseline (466.013 us; speedup 1.0000x reference)
//
#include <hip/hip_runtime.h>
#include <math.h>

#define NB 1024
#define NQ 32768
#define ND 1024
#define NL 4
#define INV_TEMP (1.0f / 0.07f)
#define NEG_INF (-INFINITY)
#define BMW 5120                 // bitmap words: 163840 bits >= max key 159980 (base=20)
#define KEYSPACE (BMW * 32)
#define NKC (ND / 64)            // 16 chunks of 64 K
#define NHC (ND / 32)            // 32 half-chunks (BK=32 steps)

// ---- workspace layout (bytes) ----
#define WS_BASE    0             // int, max label (atomicMax; 0xAA poison is negative)
#define WS_BM1     1024
#define WS_BM2     (WS_BM1 + BMW * 4)
#define WS_ACCUM   (WS_BM2 + BMW * 4)          // 3*NB*4 floats {s,p,c,pad}
#define WS_LIDX    (WS_ACCUM + 3 * NB * 4 * 4)
#define WS_MAXK    (WS_LIDX + KEYSPACE * 4)
#define WS_ZERO_END (WS_MAXK + KEYSPACE * 4)
#define WS_KAV     ((WS_ZERO_END + 255) & ~255)
#define WS_ACTA    (WS_KAV + 3 * NB * 4)
#define WS_KQV     (WS_ACTA + 3 * NB * 4)
#define WS_FBF     ((size_t)(((WS_KQV + 3 * NQ * 4) + 255) & ~255))
#define WS_FQBF    (WS_FBF + (size_t)NB * ND * 2)
#define WS_TOTAL   (WS_FQBF + (size_t)NQ * ND * 2)

typedef __attribute__((ext_vector_type(8))) short short8x;
typedef __attribute__((ext_vector_type(4))) float float4x;

__device__ inline unsigned short f2bf(float x) {
  unsigned u = __float_as_uint(x);
  u += 0x7fffu + ((u >> 16) & 1u);  // RNE
  return (unsigned short)(u >> 16);
}

__device__ inline short8x cvt8(float4 lo, float4 hi) {
  union { unsigned short u[8]; short8x v; } r;
  r.u[0] = f2bf(lo.x); r.u[1] = f2bf(lo.y); r.u[2] = f2bf(lo.z); r.u[3] = f2bf(lo.w);
  r.u[4] = f2bf(hi.x); r.u[5] = f2bf(hi.y); r.u[6] = f2bf(hi.z); r.u[7] = f2bf(hi.w);
  return r.v;
}

// ---------------------------------------------------------------------------
// kinit: zero [WS_BM1, WS_ZERO_END) + global label max -> atomicMax into ws[0]
// (ws[0] poisoned 0xAAAAAAAA = negative, so atomicMax needs no pre-zero)
// ---------------------------------------------------------------------------
__global__ __launch_bounds__(256) void kinit(
    int* __restrict__ ws, const int* __restrict__ labels,
    const int* __restrict__ labels_queue) {
  __shared__ int red[4];
  const int gid = blockIdx.x * blockDim.x + threadIdx.x;
  const int stride = gridDim.x * blockDim.x;
  for (int i = WS_BM1 / 4 + gid; i < WS_ZERO_END / 4; i += stride) ws[i] = 0;
  const int total = (NB + NQ) * NL;
  int mx = 0;
  for (int i = gid; i < total; i += stride)
    mx = max(mx, i < NB * NL ? labels[i] : labels_queue[i - NB * NL]);
  for (int off = 32; off >= 1; off >>= 1) mx = max(mx, __shfl_xor(mx, off));
  if ((threadIdx.x & 63) == 0) red[threadIdx.x >> 6] = mx;
  __syncthreads();
  if (threadIdx.x == 0) {
    int m = max(red[0], red[1]);
    m = max(m, max(red[2], red[3]));
    atomicMax(&ws[0], m);
  }
}

// ---------------------------------------------------------------------------
// k2: anchor keys + dedup via key-indexed atomicMax (last occurrence = max tid;
// level-2 keeps max ka1 per ka2 among kept2). Device-scope atomics -> coherent.
// ---------------------------------------------------------------------------
__global__ __launch_bounds__(1024) void k2_anchor(
    const int* __restrict__ labels, const int* __restrict__ basep,
    int* __restrict__ kav, int* __restrict__ acta,
    unsigned int* __restrict__ bm1, unsigned int* __restrict__ bm2,
    int* __restrict__ lastidx, int* __restrict__ maxk) {
  const int tid = threadIdx.x;
  const int b1 = basep[0] + 1;
  const int b2 = b1 * b1;
  const int b3 = b2 * b1;
  const int a0 = labels[tid * NL + 0], a1 = labels[tid * NL + 1], a2 = labels[tid * NL + 2];
  const int ka1 = a0 * b3 + a1 * b2 + a2 * b1;
  const int ka2 = a0 * b3 + a1 * b2;

  atomicMax(&lastidx[ka1], tid + 1);
  atomicOr(&bm1[ka1 >> 5], 1u << (ka1 & 31));
  __syncthreads();
  const bool kept2 = (atomicAdd(&lastidx[ka1], 0) == tid + 1);
  if (kept2) {
    atomicMax(&maxk[ka2], ka1 + 1);
    atomicOr(&bm2[ka2 >> 5], 1u << (ka2 & 31));
  }
  __syncthreads();
  const bool kept3 = kept2 && (atomicAdd(&maxk[ka2], 0) == ka1 + 1);

  kav[0 * NB + tid] = ka1;
  kav[1 * NB + tid] = ka2;
  kav[2 * NB + tid] = a0 * b3;
  acta[0 * NB + tid] = 1;
  acta[1 * NB + tid] = kept2 ? 1 : 0;
  acta[2 * NB + tid] = kept3 ? 1 : 0;
}

// ---------------------------------------------------------------------------
__global__ __launch_bounds__(256) void k3_queue(
    const int* __restrict__ labels_queue, const int* __restrict__ basep,
    const unsigned int* __restrict__ bm1, const unsigned int* __restrict__ bm2,
    int* __restrict__ kqv) {
  const int j = blockIdx.x * blockDim.x + threadIdx.x;
  if (j >= NQ) return;
  const int b1 = basep[0] + 1;
  const int b2 = b1 * b1;
  const int b3 = b2 * b1;
  const int q0 = labels_queue[j * NL + 0];
  const int q1 = labels_queue[j * NL + 1];
  const int q2 = labels_queue[j * NL + 2];
  const int kq1 = q0 * b3 + q1 * b2 + q2 * b1;
  const int kq2 = q0 * b3 + q1 * b2;
  kqv[0 * NQ + j] = kq1;
  const bool rm2 = (bm1[kq1 >> 5] >> (kq1 & 31)) & 1u;
  kqv[1 * NQ + j] = rm2 ? -1 : kq2;
  bool act3 = !rm2;
  if (act3) act3 = !((bm2[kq2 >> 5] >> (kq2 & 31)) & 1u);
  kqv[2 * NQ + j] = act3 ? q0 * b3 : -1;
}

// ---------------------------------------------------------------------------
// kcvt_tiled: fp32 -> bf16 in k4's staging order, LDS-staged so BOTH global
// reads (row-major float4) and global writes (slot-order 16B) are contiguous.
// Chunk = 128 rows x 64 K = 1024 slots of 8 bf16, slot s = koct*128 + row.
// ---------------------------------------------------------------------------
__global__ __launch_bounds__(256) void kcvt_tiled(
    const float* __restrict__ f, const float* __restrict__ fq,
    unsigned short* __restrict__ fbf, unsigned short* __restrict__ fqbf) {
  __shared__ __align__(16) unsigned short stg[8192];
  int tb = blockIdx.x;
  const float* src;
  unsigned short* dst;
  if (tb < (NB / 128) * NKC) { src = f; dst = fbf; }
  else { tb -= (NB / 128) * NKC; src = fq; dst = fqbf; }
  const int rb = tb / NKC, kc = tb % NKC;
  const int t = threadIdx.x;
#pragma unroll
  for (int i = 0; i < 4; i++) {
    const int lin = i * 256 + t;
    const int row = lin >> 3, ko = lin & 7;   // global read: coalesced row-major
    const float* p = src + (size_t)(rb * 128 + row) * ND + kc * 64 + ko * 8;
    const float4 lo = ((const float4*)p)[0];
    const float4 hi = ((const float4*)p)[1];
    *(short8x*)&stg[(ko * 128 + row) * 8] = cvt8(lo, hi);  // 8-way LDS, trivial traffic
  }
  __syncthreads();
  short8x* out = (short8x*)dst + (size_t)(rb * NKC + kc) * 1024;
#pragma unroll
  for (int i = 0; i < 4; i++)
    out[i * 256 + t] = *(const short8x*)&stg[(i * 256 + t) * 8];  // contiguous 16B stores
}

// ---------------------------------------------------------------------------
// k4: bf16 MFMA GEMM + fused 3-level epilogue.
// Block 128x128, 4 waves (2x2), BK=32, VGPR-roundtrip DOUBLE BUFFER:
// prefetch tile k+1 into registers BEFORE computing tile k; LDS write (the
// vmcnt wait point) comes AFTER the MFMA block -> load latency hidden inside
// one block; ONE barrier per iteration (no vmcnt(0)-at-barrier exposure).
// ---------------------------------------------------------------------------
__global__ __launch_bounds__(256) void k4_fused(
    const unsigned short* __restrict__ fbf, const unsigned short* __restrict__ fqbf,
    const int* __restrict__ kav, const int* __restrict__ kqv,
    float* __restrict__ accum) {
  __shared__ __align__(16) unsigned short As[2][4096];  // 512 slots * 8 bf16 each
  __shared__ __align__(16) unsigned short Bs[2][4096];

  const int t = threadIdx.x;
  const int colblk = blockIdx.x * 128;
  const int rowblk = blockIdx.y * 128;

  const int wave = t >> 6, lane = t & 63;
  const int wr = wave >> 1, wc = wave & 1;
  const int g4 = lane >> 4, ln = lane & 15;

  const unsigned short* gA = fbf + (size_t)blockIdx.y * (NKC * 8192);
  const unsigned short* gB = fqbf + (size_t)blockIdx.x * (NKC * 8192);

  float4x acc[4][4];
#pragma unroll
  for (int i = 0; i < 4; i++)
#pragma unroll
    for (int j = 0; j < 4; j++) acc[i][j] = (float4x){0.f, 0.f, 0.f, 0.f};

  // prologue: load half-chunk 0 and stage into buffer 0
  short8x ra0 = *(const short8x*)(gA + t * 8);
  short8x ra1 = *(const short8x*)(gA + (t + 256) * 8);
  short8x rb0 = *(const short8x*)(gB + t * 8);
  short8x rb1 = *(const short8x*)(gB + (t + 256) * 8);
  *(short8x*)&As[0][t * 8] = ra0;
  *(short8x*)&As[0][(t + 256) * 8] = ra1;
  *(short8x*)&Bs[0][t * 8] = rb0;
  *(short8x*)&Bs[0][(t + 256) * 8] = rb1;

  const int aoff = (g4 * 128 + wr * 64 + ln) * 8;
  const int boff = (g4 * 128 + wc * 64 + ln) * 8;

  for (int hc = 0; hc < NHC; hc++) {
    const int buf = hc & 1;
    __syncthreads();  // buffer `buf` staged; prior reads of buf^1 all complete
    if (hc + 1 < NHC) {  // issue next loads — in flight during MFMA below
      const size_t off = (size_t)(hc + 1) * 4096;
      ra0 = *(const short8x*)(gA + off + t * 8);
      ra1 = *(const short8x*)(gA + off + (t + 256) * 8);
      rb0 = *(const short8x*)(gB + off + t * 8);
      rb1 = *(const short8x*)(gB + off + (t + 256) * 8);
    }
    short8x av[4], bv[4];
#pragma unroll
    for (int rt = 0; rt < 4; rt++)
      av[rt] = *(const short8x*)&As[buf][aoff + rt * 16 * 8];
#pragma unroll
    for (int ct = 0; ct < 4; ct++)
      bv[ct] = *(const short8x*)&Bs[buf][boff + ct * 16 * 8];
#pragma unroll
    for (int rt = 0; rt < 4; rt++)
#pragma unroll
      for (int ct = 0; ct < 4; ct++)
        acc[rt][ct] = __builtin_amdgcn_mfma_f32_16x16x32_bf16(av[rt], bv[ct], acc[rt][ct], 0, 0, 0);
    if (hc + 1 < NHC) {  // vmcnt wait lands HERE, after the MFMA block
      *(short8x*)&As[buf ^ 1][t * 8] = ra0;
      *(short8x*)&As[buf ^ 1][(t + 256) * 8] = ra1;
      *(short8x*)&Bs[buf ^ 1][t * 8] = rb0;
      *(short8x*)&Bs[buf ^ 1][(t + 256) * 8] = rb1;
    }
  }

  // ---- epilogue ----
  __syncthreads();                 // all LDS reads done; alias As as eps
  float* eps = (float*)As;         // [wc 2][l 3][row 128] = 3 KB

  const int col0 = colblk + wc * 64;
  int kq[3][4];
#pragma unroll
  for (int l = 0; l < 3; l++)
#pragma unroll
    for (int ct = 0; ct < 4; ct++) kq[l][ct] = kqv[l * NQ + col0 + ct * 16 + ln];

#pragma unroll
  for (int rt = 0; rt < 4; rt++) {
    float sv[4][4], e[4][4];
#pragma unroll
    for (int ct = 0; ct < 4; ct++)
#pragma unroll
      for (int r = 0; r < 4; r++) {
        sv[ct][r] = acc[rt][ct][r] * INV_TEMP;   // |sv| <= ~14.3: no overflow
        e[ct][r] = __expf(sv[ct][r]);
      }
    const int rl0 = wr * 64 + rt * 16 + g4 * 4;
    const int rbase = rowblk + rl0;
#pragma unroll
    for (int l = 0; l < 3; l++) {
      int kal[4];
#pragma unroll
      for (int r = 0; r < 4; r++) kal[r] = kav[l * NB + rbase + r];
      float s[4] = {0.f, 0.f, 0.f, 0.f}, p[4] = {0.f, 0.f, 0.f, 0.f}, c[4] = {0.f, 0.f, 0.f, 0.f};
#pragma unroll
      for (int ct = 0; ct < 4; ct++) {
        const int kqc = kq[l][ct];
        if (kqc >= 0) {
#pragma unroll
          for (int r = 0; r < 4; r++) {
            s[r] += e[ct][r];
            if (kqc == kal[r]) { p[r] += sv[ct][r]; c[r] += 1.f; }
          }
        }
      }
      // butterfly only the dense quantity (s) across the 16 ln-lanes
#pragma unroll
      for (int off = 8; off >= 1; off >>= 1)
#pragma unroll
        for (int r = 0; r < 4; r++) s[r] += __shfl_xor(s[r], off);
      if (ln == 0) {
#pragma unroll
        for (int r = 0; r < 4; r++) eps[(wc * 3 + l) * 128 + rl0 + r] = s[r];
      }
      // sparse matched mass: direct per-lane atomics (matches are rare)
#pragma unroll
      for (int r = 0; r < 4; r++) {
        if (c[r] > 0.f) {
          float* a = &accum[(size_t)(l * NB + rbase + r) * 4];
          atomicAdd(a + 1, p[r]);
          atomicAdd(a + 2, c[r]);
        }
      }
    }
  }
  __syncthreads();
  if (t < 128) {
#pragma unroll
    for (int l = 0; l < 3; l++) {
      const float s = eps[(0 * 3 + l) * 128 + t] + eps[(1 * 3 + l) * 128 + t];
      atomicAdd(&accum[(size_t)(l * NB + rowblk + t) * 4], s);
    }
  }
}

// ---------------------------------------------------------------------------
__global__ __launch_bounds__(1024) void k5_final(
    const float* __restrict__ accum, const int* __restrict__ acta,
    float* __restrict__ out) {
  const int row = threadIdx.x;
  __shared__ float redl[16], redn[16];
  __shared__ float layerL[3];

  for (int l = 0; l < 3; l++) {
    const float s = accum[(size_t)(l * NB + row) * 4 + 0];
    const float p = accum[(size_t)(l * NB + row) * 4 + 1];
    const float c = accum[(size_t)(l * NB + row) * 4 + 2];
    float li = 0.f, fl = 0.f;
    if (acta[l * NB + row] != 0 && c > 0.f) {
      li = -(p / c - logf(s));  // row-max shift cancels exactly in logprob
      fl = 1.f;
    }
    for (int off = 32; off >= 1; off >>= 1) {
      li += __shfl_xor(li, off);
      fl += __shfl_xor(fl, off);
    }
    if ((row & 63) == 0) { redl[row >> 6] = li; redn[row >> 6] = fl; }
    __syncthreads();
    if (row == 0) {
      float sl = 0.f, sn = 0.f;
      for (int w = 0; w < 16; w++) { sl += redl[w]; sn += redn[w]; }
      layerL[l] = sl / (sn + 1e-12f);
    }
    __syncthreads();
  }

  if (row == 0) {
    const float wgt[3] = {2.0f, 1.41421356237f, 1.25992104989f};  // 2^(1/l)
    float cum = 0.f, maxlow = NEG_INF;
    for (int l = 0; l < 3; l++) {
      const float ll = fmaxf(maxlow, layerL[l]);
      cum += wgt[l] * ll;
      maxlow = fmaxf(maxlow, ll);
    }
    out[0] = cum;
  }
}

// ---------------------------------------------------------------------------
extern "C" void kernel_launch(void* const* d_in, const int* in_sizes, int n_in,
                              void* d_out, int out_size, void* d_ws, size_t ws_size,
                              hipStream_t stream) {
  const float* f      = (const float*)d_in[0];  // [1024,1024]
  const int* labels   = (const int*)d_in[1];    // [1024,4]
  const float* fq     = (const float*)d_in[2];  // [32768,1024]
  const int* labels_q = (const int*)d_in[3];    // [32768,4]
  float* out          = (float*)d_out;

  char* w = (char*)d_ws;
  int* basep          = (int*)(w + WS_BASE);
  unsigned int* bm1   = (unsigned int*)(w + WS_BM1);
  unsigned int* bm2   = (unsigned int*)(w + WS_BM2);
  float* accum        = (float*)(w + WS_ACCUM);
  int* lastidx        = (int*)(w + WS_LIDX);
  int* maxk           = (int*)(w + WS_MAXK);
  int* kav            = (int*)(w + WS_KAV);
  int* acta           = (int*)(w + WS_ACTA);
  int* kqv            = (int*)(w + WS_KQV);
  unsigned short* fbf  = (unsigned short*)(w + WS_FBF);
  unsigned short* fqbf = (unsigned short*)(w + WS_FQBF);

  kinit<<<dim3(64), dim3(256), 0, stream>>>((int*)w, labels, labels_q);
  k2_anchor<<<dim3(1), dim3(1024), 0, stream>>>(labels, basep, kav, acta, bm1, bm2, lastidx, maxk);
  k3_queue<<<dim3(NQ / 256), dim3(256), 0, stream>>>(labels_q, basep, bm1, bm2, kqv);
  kcvt_tiled<<<dim3((NB / 128) * NKC + (NQ / 128) * NKC), dim3(256), 0, stream>>>(f, fq, fbf, fqbf);
  k4_fused<<<dim3(NQ / 128, NB / 128), dim3(256), 0, stream>>>(fbf, fqbf, kav, kqv, accum);
  k5_final<<<dim3(1), dim3(1024), 0, stream>>>(accum, acta, out);
}